// Round 2
// baseline (209.712 us; speedup 1.0000x reference)
//
#include <hip/hip_runtime.h>

#define NODE_IN 64
#define EDGE_IN 32
#define GLOBAL_IN 32
#define HID 128
#define EOUT 32

typedef float f32x4 __attribute__((ext_vector_type(4)));
typedef float f32x2 __attribute__((ext_vector_type(2)));
typedef short s16x8 __attribute__((ext_vector_type(8)));
typedef unsigned short u16x8 __attribute__((ext_vector_type(8)));

// native bf16 cast (RNE); compiler fuses pairs into v_cvt_pk_bf16_f32
__device__ __forceinline__ unsigned short f2bf(float f) {
  __bf16 h = (__bf16)f;
  return __builtin_bit_cast(unsigned short, h);
}

// load 8 f32, convert, one ds_write_b128
__device__ __forceinline__ void stage8(const float* __restrict__ p,
                                       unsigned short* dst) {
  const f32x4 a = *(const f32x4*)p;
  const f32x4 b = *(const f32x4*)(p + 4);
  u16x8 v = { f2bf(a[0]), f2bf(a[1]), f2bf(a[2]), f2bf(a[3]),
              f2bf(b[0]), f2bf(b[1]), f2bf(b[2]), f2bf(b[3]) };
  *(u16x8*)dst = v;
}

// Block: 256 threads = 4 waves, tile = 64 edges.
// LDS: single 25.6 KB buffer, X[64][200] bf16 aliased with H[64][136] bf16
// (4 barriers/tile). Wave w computes H cols [32w,32w+32) with W1 columns
// permuted so each lane's two H-cols are adjacent (packed dword H-writes),
// then rows [16w,16w+16) of out with W2 columns permuted (packed f32x2 stores).
__global__ __launch_bounds__(256, 4) void edge_mlp(
    const float* __restrict__ srcp, const float* __restrict__ dstp,
    const float* __restrict__ eap, const float* __restrict__ up,
    const int* __restrict__ ebp, const float* __restrict__ W1,
    const float* __restrict__ b1, const float* __restrict__ W2,
    const float* __restrict__ b2, float* __restrict__ outp,
    int E, int ntiles)
{
  __shared__ __align__(16) unsigned short SM[64 * 200];  // 25600 B, X/H union

  const int t = threadIdx.x;
  const int wid = t >> 6;
  const int lane = t & 63;
  const int g = lane >> 4;
  const int r16 = lane & 15;

  // ---- weight fragments (once per block; L2-resident source) ----
  // layer-1 B-frag, permuted cols: MFMA (wid,nt) lane-col r16 -> H col 32w+2r+nt
  s16x8 w1f[6][2];
#pragma unroll
  for (int kk = 0; kk < 6; ++kk) {
#pragma unroll
    for (int nt = 0; nt < 2; ++nt) {
      s16x8 v;
#pragma unroll
      for (int j = 0; j < 8; ++j)
        v[j] = (short)f2bf(W1[(32*kk + 8*g + j)*HID + 32*wid + 2*r16 + nt]);
      w1f[kk][nt] = v;
    }
  }
  // layer-2 B-frag, permuted cols: lane-col r16 -> out col 2r+nt
  s16x8 w2f[4][2];
#pragma unroll
  for (int kk = 0; kk < 4; ++kk) {
#pragma unroll
    for (int nt = 0; nt < 2; ++nt) {
      s16x8 v;
#pragma unroll
      for (int j = 0; j < 8; ++j)
        v[j] = (short)f2bf(W2[(32*kk + 8*g + j)*EOUT + 2*r16 + nt]);
      w2f[kk][nt] = v;
    }
  }
  const float b1v0 = b1[32*wid + 2*r16];
  const float b1v1 = b1[32*wid + 2*r16 + 1];
  const float b2v0 = b2[2*r16];
  const float b2v1 = b2[2*r16 + 1];

  for (int tile = blockIdx.x; tile < ntiles; tile += gridDim.x) {
    const int mbase = tile * 64;

    // ---- stage X-tile (src|dest|ea|u[eb]) as bf16, b128 writes ----
#pragma unroll
    for (int k = 0; k < 2; ++k) {
      const int cid = t + 256*k;               // 0..511
      const int row = cid >> 3, c = cid & 7;
      const int grow = min(mbase + row, E - 1);
      stage8(srcp + (size_t)grow*NODE_IN + 8*c, &SM[row*200 + 8*c]);
    }
#pragma unroll
    for (int k = 0; k < 2; ++k) {
      const int cid = t + 256*k;
      const int row = cid >> 3, c = cid & 7;
      const int grow = min(mbase + row, E - 1);
      stage8(dstp + (size_t)grow*NODE_IN + 8*c, &SM[row*200 + 64 + 8*c]);
    }
    {
      const int row = t >> 2, c = t & 3;
      const int grow = min(mbase + row, E - 1);
      stage8(eap + (size_t)grow*EDGE_IN + 8*c, &SM[row*200 + 128 + 8*c]);
      const int bb = ebp[grow];
      stage8(up + (size_t)bb*GLOBAL_IN + 8*c, &SM[row*200 + 160 + 8*c]);
    }
    __syncthreads();                           // A: X staged

    // ---- layer 1: 4 m-tiles x 2 n-tiles, K=192 ----
    f32x4 acc[4][2];
    {
      const f32x4 z = {0.f, 0.f, 0.f, 0.f};
#pragma unroll
      for (int mi = 0; mi < 4; ++mi) { acc[mi][0] = z; acc[mi][1] = z; }
    }
#pragma unroll
    for (int kk = 0; kk < 6; ++kk) {
#pragma unroll
      for (int mi = 0; mi < 4; ++mi) {
        const s16x8 a = *(const s16x8*)&SM[(16*mi + r16)*200 + 32*kk + 8*g];
        acc[mi][0] = __builtin_amdgcn_mfma_f32_16x16x32_bf16(a, w1f[kk][0], acc[mi][0], 0, 0, 0);
        acc[mi][1] = __builtin_amdgcn_mfma_f32_16x16x32_bf16(a, w1f[kk][1], acc[mi][1], 0, 0, 0);
      }
    }
    __syncthreads();                           // B: all X reads done

    // ---- epilogue: +b1, relu, packed dword writes into H[64][136] ----
#pragma unroll
    for (int mi = 0; mi < 4; ++mi) {
#pragma unroll
      for (int j = 0; j < 4; ++j) {
        const float h0 = fmaxf(acc[mi][0][j] + b1v0, 0.f);
        const float h1 = fmaxf(acc[mi][1][j] + b1v1, 0.f);
        const unsigned int pk = (unsigned int)f2bf(h0) |
                                ((unsigned int)f2bf(h1) << 16);
        *(unsigned int*)&SM[(16*mi + 4*g + j)*136 + 32*wid + 2*r16] = pk;
      }
    }
    __syncthreads();                           // C: H ready

    // ---- layer 2: 16 rows/wave, K=128 ----
    f32x4 acc2[2];
    {
      const f32x4 z = {0.f, 0.f, 0.f, 0.f};
      acc2[0] = z; acc2[1] = z;
    }
#pragma unroll
    for (int kk = 0; kk < 4; ++kk) {
      const s16x8 a = *(const s16x8*)&SM[(16*wid + r16)*136 + 32*kk + 8*g];
      acc2[0] = __builtin_amdgcn_mfma_f32_16x16x32_bf16(a, w2f[kk][0], acc2[0], 0, 0, 0);
      acc2[1] = __builtin_amdgcn_mfma_f32_16x16x32_bf16(a, w2f[kk][1], acc2[1], 0, 0, 0);
    }
#pragma unroll
    for (int j = 0; j < 4; ++j) {
      const int m = mbase + 16*wid + 4*g + j;
      if (m < E) {
        f32x2 o = { acc2[0][j] + b2v0, acc2[1][j] + b2v1 };
        *(f32x2*)(outp + (size_t)m*EOUT + 2*r16) = o;
      }
    }
    __syncthreads();                           // D: H reads done before next stage
  }
}

extern "C" void kernel_launch(void* const* d_in, const int* in_sizes, int n_in,
                              void* d_out, int out_size, void* d_ws, size_t ws_size,
                              hipStream_t stream) {
  const float* srcp = (const float*)d_in[0];
  const float* dstp = (const float*)d_in[1];
  const float* eap  = (const float*)d_in[2];
  const float* up   = (const float*)d_in[3];
  const int*   ebp  = (const int*)d_in[4];
  const float* W1   = (const float*)d_in[5];
  const float* b1   = (const float*)d_in[6];
  const float* W2   = (const float*)d_in[7];
  const float* b2   = (const float*)d_in[8];
  float* outp = (float*)d_out;

  const int E = in_sizes[0] / NODE_IN;
  const int ntiles = (E + 63) / 64;
  const int grid = ntiles < 2048 ? ntiles : 2048;

  edge_mlp<<<grid, 256, 0, stream>>>(srcp, dstp, eap, up, ebp, W1, b1, W2, b2,
                                     outp, E, ntiles);
}

// Round 3
// 164.066 us; speedup vs baseline: 1.2782x; 1.2782x over previous
//
#include <hip/hip_runtime.h>

#define NODE_IN 64
#define EDGE_IN 32
#define GLOBAL_IN 32
#define HID 128
#define EOUT 32

typedef float f32x4 __attribute__((ext_vector_type(4)));
typedef float f32x2 __attribute__((ext_vector_type(2)));
typedef short s16x8 __attribute__((ext_vector_type(8)));
typedef unsigned short u16x8 __attribute__((ext_vector_type(8)));

// native bf16 cast (RNE); compiler fuses pairs into v_cvt_pk_bf16_f32
__device__ __forceinline__ unsigned short f2bf(float f) {
  __bf16 h = (__bf16)f;
  return __builtin_bit_cast(unsigned short, h);
}

// load 8 f32, convert, one ds_write_b128
__device__ __forceinline__ void stage8(const float* __restrict__ p,
                                       unsigned short* dst) {
  const f32x4 a = *(const f32x4*)p;
  const f32x4 b = *(const f32x4*)(p + 4);
  u16x8 v = { f2bf(a[0]), f2bf(a[1]), f2bf(a[2]), f2bf(a[3]),
              f2bf(b[0]), f2bf(b[1]), f2bf(b[2]), f2bf(b[3]) };
  *(u16x8*)dst = v;
}

// Block: 256 threads = 4 waves, tile = 64 edges.
// LDS: single 25.6 KB buffer, X[64][200] bf16 aliased with H[64][136] bf16
// (4 barriers/tile). NOTE: no waves-per-EU clamp — __launch_bounds__(256,4)
// drove VGPR to 64 and spilled weights to scratch (round 2: WRITE_SIZE
// 125->182MB, dur +27%). Let the allocator take ~116; 4 waves/SIMD cap puts
// 4 blocks/CU (LDS would allow 6).
__global__ __launch_bounds__(256) void edge_mlp(
    const float* __restrict__ srcp, const float* __restrict__ dstp,
    const float* __restrict__ eap, const float* __restrict__ up,
    const int* __restrict__ ebp, const float* __restrict__ W1,
    const float* __restrict__ b1, const float* __restrict__ W2,
    const float* __restrict__ b2, float* __restrict__ outp,
    int E, int ntiles)
{
  __shared__ __align__(16) unsigned short SM[64 * 200];  // 25600 B, X/H union

  const int t = threadIdx.x;
  const int wid = t >> 6;
  const int lane = t & 63;
  const int g = lane >> 4;
  const int r16 = lane & 15;

  // ---- weight fragments (once per block; L2-resident source) ----
  // layer-1 B-frag, permuted cols: MFMA (wid,nt) lane-col r16 -> H col 32w+2r+nt
  s16x8 w1f[6][2];
#pragma unroll
  for (int kk = 0; kk < 6; ++kk) {
#pragma unroll
    for (int nt = 0; nt < 2; ++nt) {
      s16x8 v;
#pragma unroll
      for (int j = 0; j < 8; ++j)
        v[j] = (short)f2bf(W1[(32*kk + 8*g + j)*HID + 32*wid + 2*r16 + nt]);
      w1f[kk][nt] = v;
    }
  }
  // layer-2 B-frag, permuted cols: lane-col r16 -> out col 2r+nt
  s16x8 w2f[4][2];
#pragma unroll
  for (int kk = 0; kk < 4; ++kk) {
#pragma unroll
    for (int nt = 0; nt < 2; ++nt) {
      s16x8 v;
#pragma unroll
      for (int j = 0; j < 8; ++j)
        v[j] = (short)f2bf(W2[(32*kk + 8*g + j)*EOUT + 2*r16 + nt]);
      w2f[kk][nt] = v;
    }
  }
  const float b1v0 = b1[32*wid + 2*r16];
  const float b1v1 = b1[32*wid + 2*r16 + 1];
  const float b2v0 = b2[2*r16];
  const float b2v1 = b2[2*r16 + 1];

  for (int tile = blockIdx.x; tile < ntiles; tile += gridDim.x) {
    const int mbase = tile * 64;

    // ---- stage X-tile (src|dest|ea|u[eb]) as bf16, b128 writes ----
#pragma unroll
    for (int k = 0; k < 2; ++k) {
      const int cid = t + 256*k;               // 0..511
      const int row = cid >> 3, c = cid & 7;
      const int grow = min(mbase + row, E - 1);
      stage8(srcp + (size_t)grow*NODE_IN + 8*c, &SM[row*200 + 8*c]);
    }
#pragma unroll
    for (int k = 0; k < 2; ++k) {
      const int cid = t + 256*k;
      const int row = cid >> 3, c = cid & 7;
      const int grow = min(mbase + row, E - 1);
      stage8(dstp + (size_t)grow*NODE_IN + 8*c, &SM[row*200 + 64 + 8*c]);
    }
    {
      const int row = t >> 2, c = t & 3;
      const int grow = min(mbase + row, E - 1);
      stage8(eap + (size_t)grow*EDGE_IN + 8*c, &SM[row*200 + 128 + 8*c]);
      const int bb = ebp[grow];
      stage8(up + (size_t)bb*GLOBAL_IN + 8*c, &SM[row*200 + 160 + 8*c]);
    }
    __syncthreads();                           // A: X staged

    // ---- layer 1: 4 m-tiles x 2 n-tiles, K=192 ----
    f32x4 acc[4][2];
    {
      const f32x4 z = {0.f, 0.f, 0.f, 0.f};
#pragma unroll
      for (int mi = 0; mi < 4; ++mi) { acc[mi][0] = z; acc[mi][1] = z; }
    }
#pragma unroll
    for (int kk = 0; kk < 6; ++kk) {
#pragma unroll
      for (int mi = 0; mi < 4; ++mi) {
        const s16x8 a = *(const s16x8*)&SM[(16*mi + r16)*200 + 32*kk + 8*g];
        acc[mi][0] = __builtin_amdgcn_mfma_f32_16x16x32_bf16(a, w1f[kk][0], acc[mi][0], 0, 0, 0);
        acc[mi][1] = __builtin_amdgcn_mfma_f32_16x16x32_bf16(a, w1f[kk][1], acc[mi][1], 0, 0, 0);
      }
    }
    __syncthreads();                           // B: all X reads done

    // ---- epilogue: +b1, relu, packed dword writes into H[64][136] ----
#pragma unroll
    for (int mi = 0; mi < 4; ++mi) {
#pragma unroll
      for (int j = 0; j < 4; ++j) {
        const float h0 = fmaxf(acc[mi][0][j] + b1v0, 0.f);
        const float h1 = fmaxf(acc[mi][1][j] + b1v1, 0.f);
        const unsigned int pk = (unsigned int)f2bf(h0) |
                                ((unsigned int)f2bf(h1) << 16);
        *(unsigned int*)&SM[(16*mi + 4*g + j)*136 + 32*wid + 2*r16] = pk;
      }
    }
    __syncthreads();                           // C: H ready

    // ---- layer 2: 16 rows/wave, K=128 ----
    f32x4 acc2[2];
    {
      const f32x4 z = {0.f, 0.f, 0.f, 0.f};
      acc2[0] = z; acc2[1] = z;
    }
#pragma unroll
    for (int kk = 0; kk < 4; ++kk) {
      const s16x8 a = *(const s16x8*)&SM[(16*wid + r16)*136 + 32*kk + 8*g];
      acc2[0] = __builtin_amdgcn_mfma_f32_16x16x32_bf16(a, w2f[kk][0], acc2[0], 0, 0, 0);
      acc2[1] = __builtin_amdgcn_mfma_f32_16x16x32_bf16(a, w2f[kk][1], acc2[1], 0, 0, 0);
    }
#pragma unroll
    for (int j = 0; j < 4; ++j) {
      const int m = mbase + 16*wid + 4*g + j;
      if (m < E) {
        f32x2 o = { acc2[0][j] + b2v0, acc2[1][j] + b2v1 };
        *(f32x2*)(outp + (size_t)m*EOUT + 2*r16) = o;
      }
    }
    __syncthreads();                           // D: H reads done before next stage
  }
}

extern "C" void kernel_launch(void* const* d_in, const int* in_sizes, int n_in,
                              void* d_out, int out_size, void* d_ws, size_t ws_size,
                              hipStream_t stream) {
  const float* srcp = (const float*)d_in[0];
  const float* dstp = (const float*)d_in[1];
  const float* eap  = (const float*)d_in[2];
  const float* up   = (const float*)d_in[3];
  const int*   ebp  = (const int*)d_in[4];
  const float* W1   = (const float*)d_in[5];
  const float* b1   = (const float*)d_in[6];
  const float* W2   = (const float*)d_in[7];
  const float* b2   = (const float*)d_in[8];
  float* outp = (float*)d_out;

  const int E = in_sizes[0] / NODE_IN;
  const int ntiles = (E + 63) / 64;
  const int grid = ntiles < 2048 ? ntiles : 2048;

  edge_mlp<<<grid, 256, 0, stream>>>(srcp, dstp, eap, up, ebp, W1, b1, W2, b2,
                                     outp, E, ntiles);
}